// Round 17
// baseline (88.948 us; speedup 1.0000x reference)
//
#include <hip/hip_runtime.h>

// Problem constants
#define NBATCH 8
#define NLQ    256
#define NLK    1024
#define NDQ    512
#define NDV    512
#define NH     128
#define NEGV   -1000000.0f
#define TANH_SCALE 2.8853900817779268f   // 2*log2(e)
#define LOG2E      1.4426950408889634f

using f16x8 = __attribute__((ext_vector_type(8))) _Float16;
using f16x4 = __attribute__((ext_vector_type(4))) _Float16;
using f16x2 = __attribute__((ext_vector_type(2))) _Float16;
using f32x4 = __attribute__((ext_vector_type(4))) float;

__device__ __forceinline__ float fast_exp2(float x) {
#if __has_builtin(__builtin_amdgcn_exp2f)
  return __builtin_amdgcn_exp2f(x);
#else
  return exp2f(x);
#endif
}
__device__ __forceinline__ float fast_rcp(float x) {
#if __has_builtin(__builtin_amdgcn_rcpf)
  return __builtin_amdgcn_rcpf(x);
#else
  return 1.0f / x;
#endif
}

// ---------------------------------------------------------------------------
// Prep: WT fp16 [2][128][512]; WT[s][n][k] = W_s[k][n]. 256 KB, L2-resident.
// ---------------------------------------------------------------------------
__global__ __launch_bounds__(256)
void prep_wT_kernel(const float* __restrict__ Wq, const float* __restrict__ Wk,
                    _Float16* __restrict__ wT) {
  const int idx = blockIdx.x * 256 + threadIdx.x;   // 0 .. 2*512*128-1
  const int n = idx & 127;
  const int k = (idx >> 7) & 511;
  const int s = idx >> 16;
  const float* W = s ? Wk : Wq;
  wT[((size_t)(s * NH + n)) * NDQ + k] = (_Float16)W[k * NH + n];
}

// ---------------------------------------------------------------------------
// Projections via fp16 MFMA, LDS-FREE, barrier-free.
// Wave = 16 rows x 64 cols (4 frags of 16x16), block = 4 waves (64 rows).
// Grid (160, 2): bx<32 -> Q (M=2048), else K (M=8192); by = n-half.
// (2 quarters per block: halves the Q/K re-read traffic vs grid(160,4).)
// vlen-skip: K-blocks whose 64 keys all lie >= vlen[b] return immediately.
// Epilogue: exp2(acc*2log2e); Q -> Eq row-major [row][h];
// K -> ekC[b][h/4][key][4] (h-chunked: 4 h-values contiguous per key).
// ---------------------------------------------------------------------------
__global__ __launch_bounds__(256)
void proj_mfma_kernel(const float* __restrict__ Q, const float* __restrict__ Kin,
                      const _Float16* __restrict__ wT, const int* __restrict__ vlen,
                      float* __restrict__ qp, float* __restrict__ ekC) {
  const int bx = blockIdx.x;
  const int nh2 = blockIdx.y;         // n-half: cols nh2*64 .. nh2*64+63
  const bool isQ = (bx < 32);
  const float* A = isQ ? Q : Kin;
  const int m0 = (isQ ? bx : bx - 32) * 64;
  const int sIdx = isQ ? 0 : 1;

  if (!isQ) {
    const int b = m0 >> 10;
    if ((m0 & 1023) >= vlen[b]) return;   // dead keys: never consumed unmasked
  }

  const int w = threadIdx.x >> 6, lane = threadIdx.x & 63;
  const int mrow = m0 + w * 16 + (lane & 15);
  const int kseg = (lane >> 4) * 8;

  const float* aBase = A + (size_t)mrow * NDQ + kseg;
  const _Float16* wtb = wT + ((size_t)(sIdx * NH + nh2 * 64 + (lane & 15))) * NDQ + kseg;

  f32x4 acc0 = {}, acc1 = {}, acc2 = {}, acc3 = {};
#pragma unroll 4
  for (int k0 = 0; k0 < NDQ; k0 += 32) {
    const float4 a0 = *(const float4*)&aBase[k0];
    const float4 a1 = *(const float4*)&aBase[k0 + 4];
    f16x8 af;
    af[0] = (_Float16)a0.x; af[1] = (_Float16)a0.y;
    af[2] = (_Float16)a0.z; af[3] = (_Float16)a0.w;
    af[4] = (_Float16)a1.x; af[5] = (_Float16)a1.y;
    af[6] = (_Float16)a1.z; af[7] = (_Float16)a1.w;
    const f16x8 b0 = *(const f16x8*)&wtb[k0];
    const f16x8 b1 = *(const f16x8*)&wtb[(size_t)16 * NDQ + k0];
    const f16x8 b2 = *(const f16x8*)&wtb[(size_t)32 * NDQ + k0];
    const f16x8 b3 = *(const f16x8*)&wtb[(size_t)48 * NDQ + k0];
    acc0 = __builtin_amdgcn_mfma_f32_16x16x32_f16(af, b0, acc0, 0, 0, 0);
    acc1 = __builtin_amdgcn_mfma_f32_16x16x32_f16(af, b1, acc1, 0, 0, 0);
    acc2 = __builtin_amdgcn_mfma_f32_16x16x32_f16(af, b2, acc2, 0, 0, 0);
    acc3 = __builtin_amdgcn_mfma_f32_16x16x32_f16(af, b3, acc3, 0, 0, 0);
  }

  const int orow = m0 + w * 16 + (lane >> 4) * 4;   // + r
  const int col0 = nh2 * 64 + (lane & 15);          // frags at +0,+16,+32,+48
  if (isQ) {
#pragma unroll
    for (int r = 0; r < 4; ++r) {
      qp[(size_t)(orow + r) * NH + col0]      = fast_exp2(acc0[r] * TANH_SCALE);
      qp[(size_t)(orow + r) * NH + col0 + 16] = fast_exp2(acc1[r] * TANH_SCALE);
      qp[(size_t)(orow + r) * NH + col0 + 32] = fast_exp2(acc2[r] * TANH_SCALE);
      qp[(size_t)(orow + r) * NH + col0 + 48] = fast_exp2(acc3[r] * TANH_SCALE);
    }
  } else {
#pragma unroll
    for (int r = 0; r < 4; ++r) {
      const int grow = orow + r;
      const int b = grow >> 10, key = grow & 1023;
      const float v0 = fast_exp2(acc0[r] * TANH_SCALE);
      const float v1 = fast_exp2(acc1[r] * TANH_SCALE);
      const float v2 = fast_exp2(acc2[r] * TANH_SCALE);
      const float v3 = fast_exp2(acc3[r] * TANH_SCALE);
      const int c0 = col0, c1 = col0 + 16, c2 = col0 + 32, c3 = col0 + 48;
      ekC[(((size_t)b * 32 + (c0 >> 2)) * NLK + key) * 4 + (c0 & 3)] = v0;
      ekC[(((size_t)b * 32 + (c1 >> 2)) * NLK + key) * 4 + (c1 & 3)] = v1;
      ekC[(((size_t)b * 32 + (c2 >> 2)) * NLK + key) * 4 + (c2 & 3)] = v2;
      ekC[(((size_t)b * 32 + (c3 >> 2)) * NLK + key) * 4 + (c3 & 3)] = v3;
    }
  }
}

// ---------------------------------------------------------------------------
// FUSED scores + masked softmax -> fp16 attn, v17.
// h-chunked ekC (R12's best-amortization layout: ONE float4 load per g = 4
// h-values of the lane's key; wave reads 1KB contiguous) x QR=4 x FULL
// occupancy: block = 1024 thr = 16 waves, wave w owns keys [w*64, w*64+64),
// 1 key/lane. Grid (64, NBATCH) = 512 blocks = 2/CU = 32 waves/CU (100%).
// Per g: 1 vmem load : 48 math instrs. Eq rows + w_v wave-uniform -> s_load.
// vlen skip: waves entirely beyond VL skip the g-loop. In-block softmax
// across 16 waves via LDS.
//   score = Wsum - 2*sum_h w*rcp(1 + Eq*Ek); Wsum cancels in softmax.
// ---------------------------------------------------------------------------
__global__ __launch_bounds__(1024)
void scores_softmax_kernel(const float* __restrict__ qp, const float* __restrict__ ekC,
                           const float* __restrict__ wv, const int* __restrict__ vlen,
                           _Float16* __restrict__ attnH) {
  const int qg = blockIdx.x;            // q group (4 rows), 0..63
  const int b  = blockIdx.y;            // batch
  const int w = threadIdx.x >> 6;       // 0..15 -> key segment of 64
  const int lane = threadIdx.x & 63;
  const int key = w * 64 + lane;

  __shared__ float redm[16][4];
  __shared__ float reds[16][4];

  const float* kbase = &ekC[(((size_t)b * 32) * NLK + key) * 4];  // + g*NLK*4
  const float* qbase = &qp[(size_t)(b * NLQ + qg * 4) * NH];
  const int VL = vlen[b];

  float acc[4] = {};
  if (w * 64 < VL) {                    // wave-uniform: skip fully-masked segments
#pragma unroll 8
    for (int g = 0; g < 32; ++g) {
      const float4 kv = *(const float4*)&kbase[(size_t)g * NLK * 4];  // per-lane, 16B
      const float4 w4 = *(const float4*)&wv[g * 4];                   // uniform
#pragma unroll
      for (int qi = 0; qi < 4; ++qi) {
        const float4 q4 = *(const float4*)&qbase[qi * NH + g * 4];    // uniform
        float a = acc[qi];
        a = fmaf(w4.x, fast_rcp(fmaf(q4.x, kv.x, 1.0f)), a);
        a = fmaf(w4.y, fast_rcp(fmaf(q4.y, kv.y, 1.0f)), a);
        a = fmaf(w4.z, fast_rcp(fmaf(q4.z, kv.z, 1.0f)), a);
        a = fmaf(w4.w, fast_rcp(fmaf(q4.w, kv.w, 1.0f)), a);
        acc[qi] = a;
      }
    }
  }

  // finalize scores with mask
  float s[4];
#pragma unroll
  for (int qi = 0; qi < 4; ++qi)
    s[qi] = (key < VL) ? -2.0f * acc[qi] : NEGV;

  // wave-level max per q-row, then cross-wave via LDS
#pragma unroll
  for (int qi = 0; qi < 4; ++qi) {
    float m = s[qi];
#pragma unroll
    for (int off = 32; off > 0; off >>= 1) m = fmaxf(m, __shfl_xor(m, off));
    if (lane == 0) redm[w][qi] = m;
  }
  __syncthreads();
  float mg[4];
#pragma unroll
  for (int qi = 0; qi < 4; ++qi) {
    float m = redm[0][qi];
#pragma unroll
    for (int ww = 1; ww < 16; ++ww) m = fmaxf(m, redm[ww][qi]);
    mg[qi] = m;
  }

  // exp + wave sum + cross-wave sum
  float p[4];
#pragma unroll
  for (int qi = 0; qi < 4; ++qi) {
    p[qi] = fast_exp2((s[qi] - mg[qi]) * LOG2E);
    float sum = p[qi];
#pragma unroll
    for (int off = 32; off > 0; off >>= 1) sum += __shfl_xor(sum, off);
    if (lane == 0) reds[w][qi] = sum;
  }
  __syncthreads();

#pragma unroll
  for (int qi = 0; qi < 4; ++qi) {
    float tot = reds[0][qi];
#pragma unroll
    for (int ww = 1; ww < 16; ++ww) tot += reds[ww][qi];
    const float inv = fast_rcp(tot);
    attnH[(size_t)(b * NLQ + qg * 4 + qi) * NLK + key] = (_Float16)(p[qi] * inv);
  }
}

// ---------------------------------------------------------------------------
// PV via fp16 MFMA: out[b] = attn[b] (256x1024 fp16) @ V[b].
// Tile M64 x N32 -> grid (4,16,8) = 512 blocks = 2 blocks/CU.
// Block 256 thr = 4 waves; K-step 32, register prefetch. vlen-adaptive:
// attn==0 for keys>=VL, K-loop stops at ceil(VL/32)*32.
// ---------------------------------------------------------------------------
__global__ __launch_bounds__(256)
void pv_mfma_kernel(const _Float16* __restrict__ attnH, const float* __restrict__ V,
                    const int* __restrict__ vlen, float* __restrict__ out) {
  const int b  = blockIdx.z;
  const int m0 = blockIdx.x * 64;
  const int n0 = blockIdx.y * 32;
  const int tid = threadIdx.x;
  const int w = tid >> 6, lane = tid & 63;
  const int kmax = (vlen[b] + 31) & ~31;   // ceil to K-step; >=32 since VL>=1

  __shared__ _Float16 aT[64][40];   // [m][k]
  __shared__ _Float16 vT[32][32];   // [n][k], swizzled

  const _Float16* aBase = attnH + (size_t)(b * NLQ + m0) * NLK;
  const float*    vBase = V + (size_t)b * NLK * NDV + n0;
  float*          oBase = out + (size_t)(b * NLQ + m0) * NDV + n0;

  const int ar = tid >> 2;               // 0..63
  const int ak = (tid & 3) * 8;          // 0,8,16,24
  const int vk = tid >> 3;               // 0..31 (k within tile)
  const int vn = (tid & 7) * 4;          // 0..28 (n within tile)
  const int vswz = ((vn >> 2) & 3) << 3;

  const int am  = w * 16 + (lane & 15);
  const int akf = (lane >> 4) * 8;
  const int bn  = lane & 15;
  const int bks = akf ^ (((bn >> 2) & 3) << 3);

  f32x4 acc0 = {}, acc1 = {};

  // prologue: prefetch tile 0 into registers
  f16x8 aReg = *(const f16x8*)&aBase[(size_t)ar * NLK + ak];
  float4 vReg = *(const float4*)&vBase[(size_t)vk * NDV + vn];

  for (int k0 = 0; k0 < kmax; k0 += 32) {
    __syncthreads();   // previous tile's LDS reads complete
    *(f16x8*)&aT[ar][ak] = aReg;
    {
      const int ks = vk ^ vswz;
      vT[vn + 0][ks] = (_Float16)vReg.x;
      vT[vn + 1][ks] = (_Float16)vReg.y;
      vT[vn + 2][ks] = (_Float16)vReg.z;
      vT[vn + 3][ks] = (_Float16)vReg.w;
    }
    __syncthreads();

    // prefetch NEXT tile while current MFMAs run
    if (k0 + 32 < kmax) {
      aReg = *(const f16x8*)&aBase[(size_t)ar * NLK + k0 + 32 + ak];
      vReg = *(const float4*)&vBase[(size_t)(k0 + 32 + vk) * NDV + vn];
    }

    const f16x8 af = *(const f16x8*)&aT[am][akf];
    const f16x8 bf0 = *(const f16x8*)&vT[ 0 + bn][bks];
    const f16x8 bf1 = *(const f16x8*)&vT[16 + bn][bks];
    acc0 = __builtin_amdgcn_mfma_f32_16x16x32_f16(af, bf0, acc0, 0, 0, 0);
    acc1 = __builtin_amdgcn_mfma_f32_16x16x32_f16(af, bf1, acc1, 0, 0, 0);
  }

  const int orow = w * 16 + (lane >> 4) * 4;
  const int ocol = lane & 15;
#pragma unroll
  for (int r = 0; r < 4; ++r) {
    oBase[(size_t)(orow + r) * NDV + ocol +  0] = acc0[r];
    oBase[(size_t)(orow + r) * NDV + ocol + 16] = acc1[r];
  }
}

// ---------------------------------------------------------------------------
extern "C" void kernel_launch(void* const* d_in, const int* in_sizes, int n_in,
                              void* d_out, int out_size, void* d_ws, size_t ws_size,
                              hipStream_t stream) {
  const float* Q    = (const float*)d_in[0];
  const float* Kin  = (const float*)d_in[1];
  const float* V    = (const float*)d_in[2];
  const int*   vlen = (const int*)d_in[3];
  const float* Wq   = (const float*)d_in[4];
  const float* Wk   = (const float*)d_in[5];
  const float* wv   = (const float*)d_in[6];
  float* out = (float*)d_out;

  float* qp  = (float*)d_ws;                    // Eq: 2048*128 row-major
  float* ekC = qp + NBATCH * NLQ * NH;          // ekC: 8*32*1024*4
  _Float16* attnH = (_Float16*)(ekC + NBATCH * NH * NLK);       // 8*256*1024 fp16
  _Float16* wT = attnH + (size_t)NBATCH * NLQ * NLK;            // 2*128*512 fp16

  hipLaunchKernelGGL(prep_wT_kernel, dim3(2 * NDQ * NH / 256), dim3(256), 0, stream,
                     Wq, Wk, wT);
  hipLaunchKernelGGL(proj_mfma_kernel, dim3(160, 2), dim3(256), 0, stream,
                     Q, Kin, wT, vlen, qp, ekC);
  hipLaunchKernelGGL(scores_softmax_kernel, dim3(64, NBATCH), dim3(1024), 0, stream,
                     qp, ekC, wv, vlen, attnH);
  hipLaunchKernelGGL(pv_mfma_kernel, dim3(NLQ / 64, NDV / 32, NBATCH), dim3(256), 0, stream,
                     attnH, V, vlen, out);
}

// Round 18
// 73.772 us; speedup vs baseline: 1.2057x; 1.2057x over previous
//
#include <hip/hip_runtime.h>

// Problem constants
#define NBATCH 8
#define NLQ    256
#define NLK    1024
#define NDQ    512
#define NDV    512
#define NH     128
#define NEGV   -1000000.0f
#define TANH_SCALE 2.8853900817779268f   // 2*log2(e)
#define LOG2E      1.4426950408889634f

using f16x8 = __attribute__((ext_vector_type(8))) _Float16;
using f16x4 = __attribute__((ext_vector_type(4))) _Float16;
using f16x2 = __attribute__((ext_vector_type(2))) _Float16;
using f32x4 = __attribute__((ext_vector_type(4))) float;

__device__ __forceinline__ float fast_exp2(float x) {
#if __has_builtin(__builtin_amdgcn_exp2f)
  return __builtin_amdgcn_exp2f(x);
#else
  return exp2f(x);
#endif
}
__device__ __forceinline__ float fast_rcp(float x) {
#if __has_builtin(__builtin_amdgcn_rcpf)
  return __builtin_amdgcn_rcpf(x);
#else
  return 1.0f / x;
#endif
}

// ---------------------------------------------------------------------------
// Prep: WT fp16 [2][128][512]; WT[s][n][k] = W_s[k][n]. 256 KB, L2-resident.
// ---------------------------------------------------------------------------
__global__ __launch_bounds__(256)
void prep_wT_kernel(const float* __restrict__ Wq, const float* __restrict__ Wk,
                    _Float16* __restrict__ wT) {
  const int idx = blockIdx.x * 256 + threadIdx.x;   // 0 .. 2*512*128-1
  const int n = idx & 127;
  const int k = (idx >> 7) & 511;
  const int s = idx >> 16;
  const float* W = s ? Wk : Wq;
  wT[((size_t)(s * NH + n)) * NDQ + k] = (_Float16)W[k * NH + n];
}

// ---------------------------------------------------------------------------
// Projections via fp16 MFMA, LDS-FREE, barrier-free.
// Wave = 16 rows x 32 cols (2 frags of 16x16), block = 4 waves (64 rows).
// Grid (160, 4): bx<32 -> Q (M=2048), else K (M=8192); by = n-quarter.
// vlen-skip: K-blocks whose 64 keys all lie >= vlen[b] return immediately.
// Epilogue: exp2(acc*2log2e); Q -> Eq row-major, K -> EkT[b][h][key].
// ---------------------------------------------------------------------------
__global__ __launch_bounds__(256)
void proj_mfma_kernel(const float* __restrict__ Q, const float* __restrict__ Kin,
                      const _Float16* __restrict__ wT, const int* __restrict__ vlen,
                      float* __restrict__ qp, float* __restrict__ ekT) {
  const int bx = blockIdx.x;
  const int nq = blockIdx.y;          // n-quarter: cols nq*32 .. nq*32+31
  const bool isQ = (bx < 32);
  const float* A = isQ ? Q : Kin;
  const int m0 = (isQ ? bx : bx - 32) * 64;
  const int sIdx = isQ ? 0 : 1;

  if (!isQ) {
    const int b = m0 >> 10;
    if ((m0 & 1023) >= vlen[b]) return;   // dead keys: never consumed unmasked
  }

  const int w = threadIdx.x >> 6, lane = threadIdx.x & 63;
  const int mrow = m0 + w * 16 + (lane & 15);
  const int kseg = (lane >> 4) * 8;

  const float* aBase = A + (size_t)mrow * NDQ + kseg;
  const _Float16* wt0 = wT + ((size_t)(sIdx * NH + nq * 32 +      (lane & 15))) * NDQ + kseg;
  const _Float16* wt1 = wT + ((size_t)(sIdx * NH + nq * 32 + 16 + (lane & 15))) * NDQ + kseg;

  f32x4 acc0 = {}, acc1 = {};
#pragma unroll 4
  for (int k0 = 0; k0 < NDQ; k0 += 32) {
    const float4 a0 = *(const float4*)&aBase[k0];
    const float4 a1 = *(const float4*)&aBase[k0 + 4];
    f16x8 af;
    af[0] = (_Float16)a0.x; af[1] = (_Float16)a0.y;
    af[2] = (_Float16)a0.z; af[3] = (_Float16)a0.w;
    af[4] = (_Float16)a1.x; af[5] = (_Float16)a1.y;
    af[6] = (_Float16)a1.z; af[7] = (_Float16)a1.w;
    const f16x8 b0 = *(const f16x8*)&wt0[k0];
    const f16x8 b1 = *(const f16x8*)&wt1[k0];
    acc0 = __builtin_amdgcn_mfma_f32_16x16x32_f16(af, b0, acc0, 0, 0, 0);
    acc1 = __builtin_amdgcn_mfma_f32_16x16x32_f16(af, b1, acc1, 0, 0, 0);
  }

  const int orow = m0 + w * 16 + (lane >> 4) * 4;   // + r
  const int col0 = nq * 32 + (lane & 15);           // frag0 col; frag1 = +16
  if (isQ) {
#pragma unroll
    for (int r = 0; r < 4; ++r) {
      qp[(size_t)(orow + r) * NH + col0]      = fast_exp2(acc0[r] * TANH_SCALE);
      qp[(size_t)(orow + r) * NH + col0 + 16] = fast_exp2(acc1[r] * TANH_SCALE);
    }
  } else {
#pragma unroll
    for (int r = 0; r < 4; ++r) {
      const int grow = orow + r;
      const int b = grow >> 10, key = grow & 1023;
      ekT[((size_t)(b * NH) + col0)      * NLK + key] = fast_exp2(acc0[r] * TANH_SCALE);
      ekT[((size_t)(b * NH) + col0 + 16) * NLK + key] = fast_exp2(acc1[r] * TANH_SCALE);
    }
  }
}

// ---------------------------------------------------------------------------
// FUSED scores + masked softmax -> fp16 attn (R16 structure) + vlen skip
// + ping-pong kv pipeline: g-loop unrolled x2 with alternating register
// sets kvA/kvB -> 8 loads in flight, zero copy-moves.
//   score = Wsum - 2*sum_h w*rcp(1 + Eq*Ek); Wsum cancels in softmax.
// ---------------------------------------------------------------------------
__global__ __launch_bounds__(512)
void scores_softmax_kernel(const float* __restrict__ qp, const float* __restrict__ ekT,
                           const float* __restrict__ wv, const int* __restrict__ vlen,
                           _Float16* __restrict__ attnH) {
  const int qg = blockIdx.x;            // q group (4 rows), 0..63
  const int b  = blockIdx.y;            // batch
  const int w = threadIdx.x >> 6;       // 0..7 -> key segment of 128
  const int lane = threadIdx.x & 63;
  const int key0 = w * 128 + lane * 2;

  __shared__ float redm[8][4];
  __shared__ float reds[8][4];

  const float* kcol  = &ekT[(size_t)b * NH * NLK + key0];       // + h*NLK
  const float* qbase = &qp[(size_t)(b * NLQ + qg * 4) * NH];
  const int VL = vlen[b];

  float2 acc[4] = {};
  if (w * 128 < VL) {                   // wave-uniform: skip fully-masked segments
    float2 kvA[4], kvB[4];
#pragma unroll
    for (int hh = 0; hh < 4; ++hh)
      kvA[hh] = *(const float2*)&kcol[(size_t)hh * NLK];

#pragma unroll
    for (int g = 0; g < 32; g += 2) {
      // stage B: load g+1's kv while g's math runs
#pragma unroll
      for (int hh = 0; hh < 4; ++hh)
        kvB[hh] = *(const float2*)&kcol[(size_t)((g + 1) * 4 + hh) * NLK];

      {
        const float4 w4 = *(const float4*)&wv[g * 4];               // uniform
        float4 q4[4];
#pragma unroll
        for (int qi = 0; qi < 4; ++qi)
          q4[qi] = *(const float4*)&qbase[qi * NH + g * 4];         // uniform
#pragma unroll
        for (int hh = 0; hh < 4; ++hh) {
          const float2 kv = kvA[hh];
          const float wl = (hh == 0) ? w4.x : (hh == 1) ? w4.y : (hh == 2) ? w4.z : w4.w;
#pragma unroll
          for (int qi = 0; qi < 4; ++qi) {
            const float qs = (hh == 0) ? q4[qi].x : (hh == 1) ? q4[qi].y
                           : (hh == 2) ? q4[qi].z : q4[qi].w;
            acc[qi].x = fmaf(wl, fast_rcp(fmaf(qs, kv.x, 1.0f)), acc[qi].x);
            acc[qi].y = fmaf(wl, fast_rcp(fmaf(qs, kv.y, 1.0f)), acc[qi].y);
          }
        }
      }

      // stage A: load g+2's kv while g+1's math runs
      if (g + 2 < 32) {
#pragma unroll
        for (int hh = 0; hh < 4; ++hh)
          kvA[hh] = *(const float2*)&kcol[(size_t)((g + 2) * 4 + hh) * NLK];
      }

      {
        const float4 w4 = *(const float4*)&wv[(g + 1) * 4];         // uniform
        float4 q4[4];
#pragma unroll
        for (int qi = 0; qi < 4; ++qi)
          q4[qi] = *(const float4*)&qbase[qi * NH + (g + 1) * 4];   // uniform
#pragma unroll
        for (int hh = 0; hh < 4; ++hh) {
          const float2 kv = kvB[hh];
          const float wl = (hh == 0) ? w4.x : (hh == 1) ? w4.y : (hh == 2) ? w4.z : w4.w;
#pragma unroll
          for (int qi = 0; qi < 4; ++qi) {
            const float qs = (hh == 0) ? q4[qi].x : (hh == 1) ? q4[qi].y
                           : (hh == 2) ? q4[qi].z : q4[qi].w;
            acc[qi].x = fmaf(wl, fast_rcp(fmaf(qs, kv.x, 1.0f)), acc[qi].x);
            acc[qi].y = fmaf(wl, fast_rcp(fmaf(qs, kv.y, 1.0f)), acc[qi].y);
          }
        }
      }
    }
  }

  // finalize scores with mask
  float2 s[4];
#pragma unroll
  for (int qi = 0; qi < 4; ++qi) {
    s[qi].x = (key0 + 0 < VL) ? -2.0f * acc[qi].x : NEGV;
    s[qi].y = (key0 + 1 < VL) ? -2.0f * acc[qi].y : NEGV;
  }

  // wave-level max per q-row, then cross-wave via LDS
#pragma unroll
  for (int qi = 0; qi < 4; ++qi) {
    float m = fmaxf(s[qi].x, s[qi].y);
#pragma unroll
    for (int off = 32; off > 0; off >>= 1) m = fmaxf(m, __shfl_xor(m, off));
    if (lane == 0) redm[w][qi] = m;
  }
  __syncthreads();
  float mg[4];
#pragma unroll
  for (int qi = 0; qi < 4; ++qi) {
    float m = redm[0][qi];
#pragma unroll
    for (int ww = 1; ww < 8; ++ww) m = fmaxf(m, redm[ww][qi]);
    mg[qi] = m;
  }

  // exp + wave sum + cross-wave sum
  float2 p[4];
#pragma unroll
  for (int qi = 0; qi < 4; ++qi) {
    p[qi].x = fast_exp2((s[qi].x - mg[qi]) * LOG2E);
    p[qi].y = fast_exp2((s[qi].y - mg[qi]) * LOG2E);
    float sum = p[qi].x + p[qi].y;
#pragma unroll
    for (int off = 32; off > 0; off >>= 1) sum += __shfl_xor(sum, off);
    if (lane == 0) reds[w][qi] = sum;
  }
  __syncthreads();

#pragma unroll
  for (int qi = 0; qi < 4; ++qi) {
    float tot = reds[0][qi];
#pragma unroll
    for (int ww = 1; ww < 8; ++ww) tot += reds[ww][qi];
    const float inv = fast_rcp(tot);
    f16x2 h;
    h[0] = (_Float16)(p[qi].x * inv);
    h[1] = (_Float16)(p[qi].y * inv);
    *(f16x2*)&attnH[(size_t)(b * NLQ + qg * 4 + qi) * NLK + key0] = h;
  }
}

// ---------------------------------------------------------------------------
// PV via fp16 MFMA: out[b] = attn[b] (256x1024 fp16) @ V[b].
// Tile M64 x N32 -> grid (4,16,8) = 512 blocks = 2 blocks/CU.
// Block 256 thr = 4 waves; K-step 32, register prefetch. vlen-adaptive:
// attn==0 for keys>=VL, K-loop stops at ceil(VL/32)*32.
// ---------------------------------------------------------------------------
__global__ __launch_bounds__(256)
void pv_mfma_kernel(const _Float16* __restrict__ attnH, const float* __restrict__ V,
                    const int* __restrict__ vlen, float* __restrict__ out) {
  const int b  = blockIdx.z;
  const int m0 = blockIdx.x * 64;
  const int n0 = blockIdx.y * 32;
  const int tid = threadIdx.x;
  const int w = tid >> 6, lane = tid & 63;
  const int kmax = (vlen[b] + 31) & ~31;   // ceil to K-step; >=32 since VL>=1

  __shared__ _Float16 aT[64][40];   // [m][k]
  __shared__ _Float16 vT[32][32];   // [n][k], swizzled

  const _Float16* aBase = attnH + (size_t)(b * NLQ + m0) * NLK;
  const float*    vBase = V + (size_t)b * NLK * NDV + n0;
  float*          oBase = out + (size_t)(b * NLQ + m0) * NDV + n0;

  const int ar = tid >> 2;               // 0..63
  const int ak = (tid & 3) * 8;          // 0,8,16,24
  const int vk = tid >> 3;               // 0..31 (k within tile)
  const int vn = (tid & 7) * 4;          // 0..28 (n within tile)
  const int vswz = ((vn >> 2) & 3) << 3;

  const int am  = w * 16 + (lane & 15);
  const int akf = (lane >> 4) * 8;
  const int bn  = lane & 15;
  const int bks = akf ^ (((bn >> 2) & 3) << 3);

  f32x4 acc0 = {}, acc1 = {};

  // prologue: prefetch tile 0 into registers
  f16x8 aReg = *(const f16x8*)&aBase[(size_t)ar * NLK + ak];
  float4 vReg = *(const float4*)&vBase[(size_t)vk * NDV + vn];

  for (int k0 = 0; k0 < kmax; k0 += 32) {
    __syncthreads();   // previous tile's LDS reads complete
    *(f16x8*)&aT[ar][ak] = aReg;
    {
      const int ks = vk ^ vswz;
      vT[vn + 0][ks] = (_Float16)vReg.x;
      vT[vn + 1][ks] = (_Float16)vReg.y;
      vT[vn + 2][ks] = (_Float16)vReg.z;
      vT[vn + 3][ks] = (_Float16)vReg.w;
    }
    __syncthreads();

    // prefetch NEXT tile while current MFMAs run
    if (k0 + 32 < kmax) {
      aReg = *(const f16x8*)&aBase[(size_t)ar * NLK + k0 + 32 + ak];
      vReg = *(const float4*)&vBase[(size_t)(k0 + 32 + vk) * NDV + vn];
    }

    const f16x8 af = *(const f16x8*)&aT[am][akf];
    const f16x8 bf0 = *(const f16x8*)&vT[ 0 + bn][bks];
    const f16x8 bf1 = *(const f16x8*)&vT[16 + bn][bks];
    acc0 = __builtin_amdgcn_mfma_f32_16x16x32_f16(af, bf0, acc0, 0, 0, 0);
    acc1 = __builtin_amdgcn_mfma_f32_16x16x32_f16(af, bf1, acc1, 0, 0, 0);
  }

  const int orow = w * 16 + (lane >> 4) * 4;
  const int ocol = lane & 15;
#pragma unroll
  for (int r = 0; r < 4; ++r) {
    oBase[(size_t)(orow + r) * NDV + ocol +  0] = acc0[r];
    oBase[(size_t)(orow + r) * NDV + ocol + 16] = acc1[r];
  }
}

// ---------------------------------------------------------------------------
extern "C" void kernel_launch(void* const* d_in, const int* in_sizes, int n_in,
                              void* d_out, int out_size, void* d_ws, size_t ws_size,
                              hipStream_t stream) {
  const float* Q    = (const float*)d_in[0];
  const float* Kin  = (const float*)d_in[1];
  const float* V    = (const float*)d_in[2];
  const int*   vlen = (const int*)d_in[3];
  const float* Wq   = (const float*)d_in[4];
  const float* Wk   = (const float*)d_in[5];
  const float* wv   = (const float*)d_in[6];
  float* out = (float*)d_out;

  float* qp  = (float*)d_ws;                    // Eq: 2048*128 row-major
  float* ekT = qp + NBATCH * NLQ * NH;          // EkT: 8*128*1024
  _Float16* attnH = (_Float16*)(ekT + NBATCH * NH * NLK);       // 8*256*1024 fp16
  _Float16* wT = attnH + (size_t)NBATCH * NLQ * NLK;            // 2*128*512 fp16

  hipLaunchKernelGGL(prep_wT_kernel, dim3(2 * NDQ * NH / 256), dim3(256), 0, stream,
                     Wq, Wk, wT);
  hipLaunchKernelGGL(proj_mfma_kernel, dim3(160, 4), dim3(256), 0, stream,
                     Q, Kin, wT, vlen, qp, ekT);
  hipLaunchKernelGGL(scores_softmax_kernel, dim3(64, NBATCH), dim3(512), 0, stream,
                     qp, ekT, wv, vlen, attnH);
  hipLaunchKernelGGL(pv_mfma_kernel, dim3(NLQ / 64, NDV / 32, NBATCH), dim3(256), 0, stream,
                     attnH, V, vlen, out);
}